// Round 3
// baseline (576.056 us; speedup 1.0000x reference)
//
#include <hip/hip_runtime.h>
#include <cstdint>

typedef __bf16          bf16x8 __attribute__((ext_vector_type(8)));
typedef float           f32x4  __attribute__((ext_vector_type(4)));
typedef unsigned short  u16x8  __attribute__((ext_vector_type(8)));

#define MFMA16(a,b,c) __builtin_amdgcn_mfma_f32_16x16x32_bf16((a),(b),(c),0,0,0)

__device__ __forceinline__ float rcpf(float x) { return __builtin_amdgcn_rcpf(x); }
__device__ __forceinline__ float ex2(float x)  { return __builtin_amdgcn_exp2f(x); }

// truncation hi/lo split: hi = top16(v), lo = trunc16(v - hi).
__device__ __forceinline__ void split2(float v, unsigned short& hi, unsigned short& lo) {
    unsigned u = __builtin_bit_cast(unsigned, v);
    hi = (unsigned short)(u >> 16);
    float rem = v - __builtin_bit_cast(float, u & 0xffff0000u);
    lo = (unsigned short)(__builtin_bit_cast(unsigned, rem) >> 16);
}
__device__ __forceinline__ __bf16 bfbits(unsigned short b) { return __builtin_bit_cast(__bf16, b); }

// ---------------------------------------------------------------------------
// 8-wave blocks: 2 sample-groups x 4 roles {L0-main, L0-help, L1-main, L1-help}.
// mains: full cell MFMA + elementwise rows r=0..2 + write acc r=3 to xfer.
// helpers: input projection (row-split) in phase 1; elementwise row r=3 in
// phase 2 (reads xfer). Layer pipeline skew: L1 processes step t-1.
// Biases folded into weight row k=13 against a constant 1.0 in staging (the
// k=13 pad row of every state image; preserved because h-writes are col<13
// masked). FORGET_BIAS folded into the f-gate bias. Acc init = 0.
// Staging [grp][buf][plane hi/lo][m*24 + k], m = sample row, k = unit.
// ---------------------------------------------------------------------------

constexpr float KL = 1.4426950408889634f;   // log2(e)

__global__ __launch_bounds__(512, 8)
void lstm_fused(const float* __restrict__ x,
                const float* __restrict__ w_hidden,
                const float* __restrict__ b_hidden,
                const float* __restrict__ k0,
                const float* __restrict__ b0,
                const float* __restrict__ k1,
                const float* __restrict__ b1,
                const float* __restrict__ w_out,
                const float* __restrict__ b_out,
                float* __restrict__ out)
{
    __shared__ __attribute__((aligned(16))) unsigned short xh_s[2][2][2][384];
    __shared__ __attribute__((aligned(16))) unsigned short h0_s[2][2][2][384];
    __shared__ __attribute__((aligned(16))) unsigned short h1_s[2][2][2][384];
    __shared__ __attribute__((aligned(16))) f32x4 xfer[2][2][64];

    const int lane   = threadIdx.x & 63;
    const int wv     = threadIdx.x >> 6;
    const int grp    = wv >> 2;
    const int role   = wv & 3;
    const int layer  = role >> 1;
    const int helper = role & 1;
    const int col    = lane & 15;
    const int q      = lane >> 4;
    const int qh     = q & 1;
    const int s0     = (blockIdx.x * 2 + grp) * 16;

    // ---- init staging: zeros + 1.0 at hi-plane k=13 of every row ----
    {
        unsigned short* a0 = &xh_s[0][0][0][0];
        unsigned short* a1 = &h0_s[0][0][0][0];
        unsigned short* a2 = &h1_s[0][0][0][0];
        for (int idx = threadIdx.x; idx < 3072; idx += 512) {
            unsigned short v = ((idx % 24) == 13 && ((idx / 384) & 1) == 0) ? (unsigned short)0x3F80 : (unsigned short)0;
            a0[idx] = v; a1[idx] = v; a2[idx] = v;
        }
    }

    // ---- weights. Role aliasing: mains use Kh[0..3]/Kl[0..3] (LSTM kernel);
    //      helpers use Kh[0]=Ph (proj hi), Kh[1]=Pl (proj lo). Shared storage
    //      keeps the register union at 32 VGPRs. ----
    bf16x8 Kh[4], Kl[4];
    if (!helper) {
        const float* kp = layer ? k1 : k0;
        const float* bb = layer ? b1 : b0;
        #pragma unroll
        for (int g = 0; g < 4; ++g) {
            bf16x8 hv{}, lv{};
            #pragma unroll
            for (int j = 0; j < 8; ++j) {
                int k = 8 * q + j;
                float w = 0.f;
                if (col < 13) {
                    if (k < 13)                 w = kp[k * 52 + 13 * g + col];
                    else if (k == 13)           w = bb[13 * g + col] + (g == 2 ? 1.f : 0.f);  // bias row (+FORGET_BIAS on f)
                    else if (k >= 16 && k < 29) w = kp[(13 + k - 16) * 52 + 13 * g + col];
                }
                unsigned short h_, l_;
                split2(w, h_, l_);
                hv[j] = bfbits(h_); lv[j] = bfbits(l_);
            }
            Kh[g] = hv; Kl[g] = lv;
        }
    } else {
        bf16x8 hv{}, lv{};
        #pragma unroll
        for (int j = 0; j < 8; ++j) {
            int k = 8 * q + j;
            float w = 0.f;
            if (col < 13) {
                if (k < 13)       w = w_hidden[k * 13 + col];
                else if (k == 13) w = b_hidden[col];            // proj bias row
            }
            unsigned short h_, l_;
            split2(w, h_, l_);
            hv[j] = bfbits(h_); lv[j] = bfbits(l_);
        }
        Kh[0] = hv; Kh[1] = lv;
    }

    const float* xrow = x + (size_t)(s0 + col) * 1300;
    float cst0 = 0.f, cst1 = 0.f, cst2 = 0.f;   // mains: rows 0..2; helpers: cst0 = row 3

    // reduced-trans elementwise: 5 exp + 2 rcp per value
    auto elem = [&](float zi, float zj, float zf, float zo, float& c) -> float {
        float a   = ex2(-KL * zi);
        float b   = ex2(-2.f * KL * zj);
        float fe  = ex2(-KL * zf);
        float g   = ex2(-KL * zo);
        float opa = 1.f + a, opb = 1.f + b, opf = 1.f + fe;
        float pab = opa * opb;
        float r1  = rcpf(pab * opf);
        float cn  = fmaf(c, pab, (1.f - b) * opf) * r1;   // c*sig(f) + sig(i)*tanh(j)
        c = cn;
        float d   = ex2(-2.f * KL * cn);
        float r2  = rcpf((1.f + d) * (1.f + g));
        return (1.f - d) * r2;                            // tanh(cn)*sig(o)
    };

    auto cell_main = [&](const unsigned short* inH, const unsigned short* hidH,
                         unsigned short* outH) {
        const unsigned short* pA = (q < 2) ? inH : hidH;
        bf16x8 ah = __builtin_bit_cast(bf16x8, *(const u16x8*)(pA + col * 24 + 8 * qh));
        bf16x8 al = __builtin_bit_cast(bf16x8, *(const u16x8*)(pA + 384 + col * 24 + 8 * qh));
        f32x4 z0 = {0.f,0.f,0.f,0.f}, z1 = z0, z2 = z0, z3 = z0;
        z0 = MFMA16(ah, Kh[0], z0); z0 = MFMA16(al, Kh[0], z0); z0 = MFMA16(ah, Kl[0], z0);
        z1 = MFMA16(ah, Kh[1], z1); z1 = MFMA16(al, Kh[1], z1); z1 = MFMA16(ah, Kl[1], z1);
        z2 = MFMA16(ah, Kh[2], z2); z2 = MFMA16(al, Kh[2], z2); z2 = MFMA16(ah, Kl[2], z2);
        z3 = MFMA16(ah, Kh[3], z3); z3 = MFMA16(al, Kh[3], z3); z3 = MFMA16(ah, Kl[3], z3);
        xfer[grp][layer][lane] = (f32x4){z0[3], z1[3], z2[3], z3[3]};
        float* cs[3] = {&cst0, &cst1, &cst2};
        #pragma unroll
        for (int r = 0; r < 3; ++r) {
            float hv = elem(z0[r], z1[r], z2[r], z3[r], *cs[r]);
            unsigned short hh, hl;
            split2(hv, hh, hl);
            if (col < 13) {
                outH[(4 * q + r) * 24 + col]       = hh;
                outH[384 + (4 * q + r) * 24 + col] = hl;
            }
        }
    };

    auto cell_help = [&](unsigned short* outH) {
        f32x4 z = xfer[grp][layer][lane];
        float hv = elem(z[0], z[1], z[2], z[3], cst0);
        unsigned short hh, hl;
        split2(hv, hh, hl);
        if (col < 13) {
            outH[(4 * q + 3) * 24 + col]       = hh;
            outH[384 + (4 * q + 3) * 24 + col] = hl;
        }
    };

    auto proj = [&](int t, unsigned short* oH) {
        bf16x8 axh{}, axl{};
        if (q < 2) {
            const float* p = xrow + t * 13;
            #pragma unroll
            for (int j = 0; j < 8; ++j) {
                int k  = 8 * q + j;
                int kk = k > 12 ? 12 : k;           // clamp keeps loads in-bounds
                float v = p[kk];
                if (k > 12) v = 0.f;
                unsigned short h_, l_;
                split2(v, h_, l_);
                axh[j] = bfbits(h_); axl[j] = bfbits(l_);
            }
            if (q == 1) { axh[5] = bfbits(0x3F80); axl[5] = bfbits(0); }  // k=13 -> 1.0 (bias row)
        }
        f32x4 zp = {0.f,0.f,0.f,0.f};
        zp = MFMA16(axh, Kh[0], zp);   // Kh[0]=Ph, Kh[1]=Pl (helper aliasing)
        zp = MFMA16(axl, Kh[0], zp);
        zp = MFMA16(axh, Kh[1], zp);
        #pragma unroll
        for (int rr = 0; rr < 2; ++rr) {
            int r = 2 * layer + rr;                 // role1 rows {0,1}, role3 rows {2,3}
            float v = fmaxf(zp[r], 0.f);
            unsigned short hh, hl;
            split2(v, hh, hl);
            if (col < 13) {
                oH[(4 * q + r) * 24 + col]       = hh;
                oH[384 + (4 * q + r) * 24 + col] = hl;
            }
        }
    };

    __syncthreads();            // staging init visible
    if (helper) proj(0, &xh_s[grp][0][0][0]);
    __syncthreads();

    for (int i = 0; i <= 100; ++i) {
        int p = i & 1;
        // ---- phase 1 ----
        if (!helper) {
            if (layer == 0) {
                if (i < 100)
                    cell_main(&xh_s[grp][p][0][0], &h0_s[grp][p ^ 1][0][0], &h0_s[grp][p][0][0]);
            } else {
                if (i >= 1)
                    cell_main(&h0_s[grp][p ^ 1][0][0], &h1_s[grp][p][0][0], &h1_s[grp][p ^ 1][0][0]);
            }
        } else {
            if (i < 99) proj(i + 1, &xh_s[grp][p ^ 1][0][0]);
        }
        __syncthreads();
        // ---- phase 2 (helpers finish row 3) ----
        if (helper) {
            if (layer == 0) { if (i < 100) cell_help(&h0_s[grp][p][0][0]); }
            else            { if (i >= 1)  cell_help(&h1_s[grp][p ^ 1][0][0]); }
        }
        __syncthreads();
    }

    // ---- output projection: role3 per group; h1(99) lives in buf 1 ----
    if (helper && layer == 1) {
        bf16x8 Oh{}, Ol{};
        #pragma unroll
        for (int j = 0; j < 8; ++j) {
            int k = 8 * q + j;
            float w = 0.f;
            if (col < 4) {
                if (k < 13)       w = w_out[k * 4 + col];
                else if (k == 13) w = b_out[col];
            }
            unsigned short h_, l_;
            split2(w, h_, l_);
            Oh[j] = bfbits(h_); Ol[j] = bfbits(l_);
        }
        const unsigned short* pA = &h1_s[grp][1][0][0];
        bf16x8 ah = __builtin_bit_cast(bf16x8, *(const u16x8*)(pA + col * 24 + 8 * qh));
        bf16x8 al = __builtin_bit_cast(bf16x8, *(const u16x8*)(pA + 384 + col * 24 + 8 * qh));
        f32x4 zf = {0.f,0.f,0.f,0.f};
        zf = MFMA16(ah, Oh, zf);
        zf = MFMA16(al, Oh, zf);
        zf = MFMA16(ah, Ol, zf);
        if (col < 4) {
            #pragma unroll
            for (int r = 0; r < 4; ++r)
                out[(size_t)(s0 + 4 * q + r) * 4 + col] = zf[r];
        }
    }
}

extern "C" void kernel_launch(void* const* d_in, const int* in_sizes, int n_in,
                              void* d_out, int out_size, void* d_ws, size_t ws_size,
                              hipStream_t stream) {
    (void)in_sizes; (void)n_in; (void)d_ws; (void)ws_size; (void)out_size;
    lstm_fused<<<dim3(1024), dim3(512), 0, stream>>>(
        (const float*)d_in[0], (const float*)d_in[1], (const float*)d_in[2],
        (const float*)d_in[3], (const float*)d_in[4], (const float*)d_in[5],
        (const float*)d_in[6], (const float*)d_in[7], (const float*)d_in[8],
        (float*)d_out);
}

// Round 5
// 372.467 us; speedup vs baseline: 1.5466x; 1.5466x over previous
//
#include <hip/hip_runtime.h>
#include <cstdint>

typedef __bf16          bf16x8 __attribute__((ext_vector_type(8)));
typedef float           f32x4  __attribute__((ext_vector_type(4)));
typedef unsigned short  u16x8  __attribute__((ext_vector_type(8)));

#define MFMA16(a,b,c) __builtin_amdgcn_mfma_f32_16x16x32_bf16((a),(b),(c),0,0,0)

__device__ __forceinline__ float rcpf(float x) { return __builtin_amdgcn_rcpf(x); }
__device__ __forceinline__ float ex2(float x)  { return __builtin_amdgcn_exp2f(x); }

// truncation hi/lo split: hi = top16(v), lo = trunc16(v - hi).
__device__ __forceinline__ void split2(float v, unsigned short& hi, unsigned short& lo) {
    unsigned u = __builtin_bit_cast(unsigned, v);
    hi = (unsigned short)(u >> 16);
    float rem = v - __builtin_bit_cast(float, u & 0xffff0000u);
    lo = (unsigned short)(__builtin_bit_cast(unsigned, rem) >> 16);
}
__device__ __forceinline__ __bf16 bfbits(unsigned short b) { return __builtin_bit_cast(__bf16, b); }

// ---------------------------------------------------------------------------
// R2 skeleton (2 roles, 4 waves/block, VGPR-resident weights, 1 barrier/step)
// + R3's verified VALU cuts (7-trans elementwise, bias row k=13 vs 1.0 in
// staging pos 13, epilogue-only output weights).
// Role 0: lstm0 step i. Role 1: lstm1 step i-1 + input proj step i+1.
// Staging images [..][plane hi/lo][m*24 + k]; pos 13 of every row = 1.0 (hi)
// so weight row k=13 (bias; +FORGET_BIAS on f-gate) supplies the bias; weight
// rows k=29..31 are zero so pos 13 is harmless when an image serves as the
// hidden part. h/xh writes are col<13-masked to preserve pos 13.
// R3 lesson: do NOT chase 8 waves/SIMD — 32 weight VGPRs force spills
// (WRITE_SIZE 79 MB). launch_bounds(256,4) keeps budget 128, no spill.
// R4 lesson: ext_vector elements are rvalues — cell state must be float[4].
// ---------------------------------------------------------------------------

constexpr float KL = 1.4426950408889634f;   // log2(e)

__global__ __launch_bounds__(256, 4)
void lstm_fused(const float* __restrict__ x,
                const float* __restrict__ w_hidden,
                const float* __restrict__ b_hidden,
                const float* __restrict__ k0,
                const float* __restrict__ b0,
                const float* __restrict__ k1,
                const float* __restrict__ b1,
                const float* __restrict__ w_out,
                const float* __restrict__ b_out,
                float* __restrict__ out)
{
    __shared__ __attribute__((aligned(16))) unsigned short xh_s[2][2][2][384];
    __shared__ __attribute__((aligned(16))) unsigned short h0_s[2][2][2][384];
    __shared__ __attribute__((aligned(16))) unsigned short h1_s[2][2][384];

    const int lane = threadIdx.x & 63;
    const int wv   = threadIdx.x >> 6;
    const int grp  = wv >> 1;
    const int role = wv & 1;
    const int col  = lane & 15;
    const int q    = lane >> 4;
    const int qh   = q & 1;
    const int s0   = (blockIdx.x * 2 + grp) * 16;

    // ---- init staging: zeros + 1.0 at hi-plane pos 13 of every row ----
    {
        unsigned short* a0 = &xh_s[0][0][0][0];
        unsigned short* a1 = &h0_s[0][0][0][0];
        for (int idx = threadIdx.x; idx < 3072; idx += 256) {
            unsigned short v = ((idx % 24) == 13 && ((idx / 384) & 1) == 0)
                             ? (unsigned short)0x3F80 : (unsigned short)0;
            a0[idx] = v; a1[idx] = v;
        }
        unsigned short* a2 = &h1_s[0][0][0];
        for (int idx = threadIdx.x; idx < 1536; idx += 256) {
            unsigned short v = ((idx % 24) == 13 && ((idx / 384) & 1) == 0)
                             ? (unsigned short)0x3F80 : (unsigned short)0;
            a2[idx] = v;
        }
    }

    // ---- role-selected LSTM weights as B-fragments (hi/lo), bias row k=13 ----
    const float* kp = role ? k1 : k0;
    const float* bb = role ? b1 : b0;
    bf16x8 Kh[4], Kl[4];
    #pragma unroll
    for (int g = 0; g < 4; ++g) {
        bf16x8 hv{}, lv{};
        #pragma unroll
        for (int j = 0; j < 8; ++j) {
            int k = 8 * q + j;
            float w = 0.f;
            if (col < 13) {
                if (k < 13)                 w = kp[k * 52 + 13 * g + col];
                else if (k == 13)           w = bb[13 * g + col] + (g == 2 ? 1.f : 0.f); // +FORGET_BIAS on f
                else if (k >= 16 && k < 29) w = kp[(13 + k - 16) * 52 + 13 * g + col];
            }
            unsigned short h_, l_;
            split2(w, h_, l_);
            hv[j] = bfbits(h_); lv[j] = bfbits(l_);
        }
        Kh[g] = hv; Kl[g] = lv;
    }

    // ---- proj weights (role 1 only) ----
    bf16x8 Ph{}, Pl{};
    if (role) {
        #pragma unroll
        for (int j = 0; j < 8; ++j) {
            int k = 8 * q + j;
            float w = 0.f;
            if (col < 13) {
                if (k < 13)       w = w_hidden[k * 13 + col];
                else if (k == 13) w = b_hidden[col];
            }
            unsigned short h_, l_;
            split2(w, h_, l_);
            Ph[j] = bfbits(h_); Pl[j] = bfbits(l_);
        }
    }

    const float* xrow = x + (size_t)(s0 + col) * 1300;

    // 7-trans elementwise (verified R3): 5 exp + 2 rcp per value
    auto elem = [&](float zi, float zj, float zf, float zo, float& c) -> float {
        float a   = ex2(-KL * zi);
        float b   = ex2(-2.f * KL * zj);
        float fe  = ex2(-KL * zf);
        float g   = ex2(-KL * zo);
        float opa = 1.f + a, opb = 1.f + b, opf = 1.f + fe;
        float pab = opa * opb;
        float r1  = rcpf(pab * opf);
        float cn  = fmaf(c, pab, (1.f - b) * opf) * r1;   // c*sig(f) + sig(i)*tanh(j)
        c = cn;
        float d   = ex2(-2.f * KL * cn);
        float r2  = rcpf((1.f + d) * (1.f + g));
        return (1.f - d) * r2;                            // tanh(cn)*sig(o)
    };

    auto cell = [&](const unsigned short* inH, const unsigned short* hidH,
                    unsigned short* outH, float* cst) {
        const unsigned short* pA = (q < 2) ? inH : hidH;
        bf16x8 ah = __builtin_bit_cast(bf16x8, *(const u16x8*)(pA + col * 24 + 8 * qh));
        bf16x8 al = __builtin_bit_cast(bf16x8, *(const u16x8*)(pA + 384 + col * 24 + 8 * qh));
        f32x4 z0 = {0.f,0.f,0.f,0.f}, z1 = z0, z2 = z0, z3 = z0;
        z0 = MFMA16(ah, Kh[0], z0); z0 = MFMA16(al, Kh[0], z0); z0 = MFMA16(ah, Kl[0], z0);
        z1 = MFMA16(ah, Kh[1], z1); z1 = MFMA16(al, Kh[1], z1); z1 = MFMA16(ah, Kl[1], z1);
        z2 = MFMA16(ah, Kh[2], z2); z2 = MFMA16(al, Kh[2], z2); z2 = MFMA16(ah, Kl[2], z2);
        z3 = MFMA16(ah, Kh[3], z3); z3 = MFMA16(al, Kh[3], z3); z3 = MFMA16(ah, Kl[3], z3);
        #pragma unroll
        for (int r = 0; r < 4; ++r) {
            float hv = elem(z0[r], z1[r], z2[r], z3[r], cst[r]);
            unsigned short hh, hl;
            split2(hv, hh, hl);
            if (col < 13) {
                outH[(4 * q + r) * 24 + col]       = hh;
                outH[384 + (4 * q + r) * 24 + col] = hl;
            }
        }
    };

    auto proj = [&](int t, unsigned short* oH) {
        bf16x8 axh{}, axl{};
        if (q < 2) {
            const float* p = xrow + t * 13;
            #pragma unroll
            for (int j = 0; j < 8; ++j) {
                int k  = 8 * q + j;
                int kk = k > 12 ? 12 : k;     // clamp keeps loads in-bounds
                float v = p[kk];
                if (k > 12) v = 0.f;
                unsigned short h_, l_;
                split2(v, h_, l_);
                axh[j] = bfbits(h_); axl[j] = bfbits(l_);
            }
            if (q == 1) { axh[5] = bfbits(0x3F80); axl[5] = bfbits(0); }  // k=13 -> 1.0 (bias row)
        }
        f32x4 zp = {0.f,0.f,0.f,0.f};
        zp = MFMA16(axh, Ph, zp);
        zp = MFMA16(axl, Ph, zp);
        zp = MFMA16(axh, Pl, zp);
        #pragma unroll
        for (int r = 0; r < 4; ++r) {
            float v = fmaxf(zp[r], 0.f);
            unsigned short hh, hl;
            split2(v, hh, hl);
            if (col < 13) {
                oH[(4 * q + r) * 24 + col]       = hh;
                oH[384 + (4 * q + r) * 24 + col] = hl;
            }
        }
    };

    float cst[4] = {0.f, 0.f, 0.f, 0.f};

    __syncthreads();                 // staging init visible
    if (role) proj(0, &xh_s[grp][0][0][0]);
    __syncthreads();

    for (int i = 0; i <= 100; ++i) {
        int p = i & 1;
        if (role == 0) {
            if (i < 100)
                cell(&xh_s[grp][p][0][0], &h0_s[grp][p ^ 1][0][0],
                     &h0_s[grp][p][0][0], cst);
        } else {
            if (i >= 1)
                cell(&h0_s[grp][p ^ 1][0][0], &h1_s[grp][0][0],
                     &h1_s[grp][0][0], cst);           // h1 in-place (own wave only)
            if (i < 99) proj(i + 1, &xh_s[grp][p ^ 1][0][0]);
        }
        __syncthreads();
    }

    // ---- output projection (role 1 holds final h1; bias row k=13 = b_out) ----
    if (role) {
        bf16x8 Oh{}, Ol{};
        #pragma unroll
        for (int j = 0; j < 8; ++j) {
            int k = 8 * q + j;
            float w = 0.f;
            if (col < 4) {
                if (k < 13)       w = w_out[k * 4 + col];
                else if (k == 13) w = b_out[col];
            }
            unsigned short h_, l_;
            split2(w, h_, l_);
            Oh[j] = bfbits(h_); Ol[j] = bfbits(l_);
        }
        const unsigned short* pA = &h1_s[grp][0][0];
        bf16x8 ah = __builtin_bit_cast(bf16x8, *(const u16x8*)(pA + col * 24 + 8 * qh));
        bf16x8 al = __builtin_bit_cast(bf16x8, *(const u16x8*)(pA + 384 + col * 24 + 8 * qh));
        f32x4 zf = {0.f,0.f,0.f,0.f};
        zf = MFMA16(ah, Oh, zf);
        zf = MFMA16(al, Oh, zf);
        zf = MFMA16(ah, Ol, zf);
        if (col < 4) {
            #pragma unroll
            for (int r = 0; r < 4; ++r)
                out[(size_t)(s0 + 4 * q + r) * 4 + col] = zf[r];
        }
    }
}

extern "C" void kernel_launch(void* const* d_in, const int* in_sizes, int n_in,
                              void* d_out, int out_size, void* d_ws, size_t ws_size,
                              hipStream_t stream) {
    (void)in_sizes; (void)n_in; (void)d_ws; (void)ws_size; (void)out_size;
    lstm_fused<<<dim3(1024), dim3(256), 0, stream>>>(
        (const float*)d_in[0], (const float*)d_in[1], (const float*)d_in[2],
        (const float*)d_in[3], (const float*)d_in[4], (const float*)d_in[5],
        (const float*)d_in[6], (const float*)d_in[7], (const float*)d_in[8],
        (float*)d_out);
}